// Round 10
// baseline (204.421 us; speedup 1.0000x reference)
//
#include <hip/hip_runtime.h>
#include <hip/hip_bf16.h>
#include <math.h>

typedef __bf16 bf16_t;
typedef __bf16 bf16x8 __attribute__((ext_vector_type(8)));
typedef __bf16 bf16x4 __attribute__((ext_vector_type(4)));
typedef float floatx4 __attribute__((ext_vector_type(4)));

// Problem: B=2, S=2048, H=1024, NH=16, D=64, M=B*S=4096. All I/O fp32.
// softmax scale 1/32 and log2(e) folded into Q projection epilogue:
#define QSCALE 0.045084222f  // 0.03125 * 1.4426950408889634

__device__ __forceinline__ void gload_lds16(const bf16_t* g, bf16_t* l) {
  __builtin_amdgcn_global_load_lds(
      (const __attribute__((address_space(1))) void*)(g),
      (__attribute__((address_space(3))) void*)(l), 16, 0, 0);
}

__device__ __forceinline__ float fast_exp2(float x) {
  float r;
  asm("v_exp_f32 %0, %1" : "=v"(r) : "v"(x));
  return r;
}

// ---------------------------------------------------------------------------
// Kernel 0: prep (merged). blocks x<2048: cast q/k/v fp32->bf16 contiguous.
// blocks x>=2048: transpose+cast wq/wk/wv [K][N] -> bf16 [N][K].
// grid (3072, 3), block 256.
// ---------------------------------------------------------------------------
__global__ __launch_bounds__(256) void prep_k(
    const float* __restrict__ q, const float* __restrict__ k,
    const float* __restrict__ v, const float* __restrict__ wq,
    const float* __restrict__ wk, const float* __restrict__ wv,
    bf16_t* __restrict__ xb, bf16_t* __restrict__ wt) {
  const int z = blockIdx.y;
  const int t = threadIdx.x;
  if (blockIdx.x < 2048) {
    const float* src = (z == 0) ? q : (z == 1) ? k : v;
    bf16_t* dst = xb + (size_t)z * 4194304u;
    const int i = (blockIdx.x * 256 + t) * 8;
    float4 f0 = *(const float4*)(src + i);
    float4 f1 = *(const float4*)(src + i + 4);
    bf16x8 hv;
    hv[0] = (bf16_t)f0.x; hv[1] = (bf16_t)f0.y;
    hv[2] = (bf16_t)f0.z; hv[3] = (bf16_t)f0.w;
    hv[4] = (bf16_t)f1.x; hv[5] = (bf16_t)f1.y;
    hv[6] = (bf16_t)f1.z; hv[7] = (bf16_t)f1.w;
    *(bf16x8*)(dst + i) = hv;
  } else {
    __shared__ float tile[32][33];
    const int bi = blockIdx.x - 2048;
    const int bx = bi & 31, by = bi >> 5;
    const float* src = (z == 0) ? wq : (z == 1) ? wk : wv;
    bf16_t* dst = wt + (size_t)z * 1048576u;
    const int tx = t & 31, ty = t >> 5;
    const int x = bx * 32 + tx, y = by * 32 + ty;
#pragma unroll
    for (int i = 0; i < 32; i += 8)
      tile[ty + i][tx] = src[(size_t)(y + i) * 1024 + x];
    __syncthreads();
    const int x2 = by * 32 + tx, y2 = bx * 32 + ty;
#pragma unroll
    for (int i = 0; i < 32; i += 8)
      dst[(size_t)(y2 + i) * 1024 + x2] = (bf16_t)tile[tx][ty + i];
  }
}

// ---------------------------------------------------------------------------
// Kernel 1: C = Xb @ W + b, all-bf16 m97-style loop: both operands staged via
// global_load_lds w16 into single-buffered 32 KB LDS, 2 barriers/iter, BK=64,
// 128x128 tile. XOR-swizzled LDS (chunk ^= row&7, conflict-free). XCD-aware
// grid (x=m-index). Q/K operand-swapped epilogues (lane holds 4 consecutive
// d); V unswapped (4 consecutive s). grid (32,8,3), block 256.
// ---------------------------------------------------------------------------
__global__ __launch_bounds__(256) void qkv_gemm_k(
    const bf16_t* __restrict__ xb3, const bf16_t* __restrict__ wt3,
    const float* __restrict__ bq, const float* __restrict__ bk,
    const float* __restrict__ bv, bf16_t* __restrict__ Qh,
    bf16_t* __restrict__ Kh, bf16_t* __restrict__ Vt) {
  const int proj = blockIdx.z;
  const bf16_t* X = xb3 + (size_t)proj * 4194304u;
  const bf16_t* Wt = wt3 + (size_t)proj * 1048576u;
  const float* bias = (proj == 0) ? bq : (proj == 1) ? bk : bv;

  __shared__ __align__(16) bf16_t As[128 * 64];  // 16 KB
  __shared__ __align__(16) bf16_t Bs[128 * 64];  // 16 KB

  const int t = threadIdx.x;
  const int lane = t & 63;
  const int w = t >> 6;
  const int wm = (w >> 1) * 64;
  const int wn = (w & 1) * 64;
  const int m0 = blockIdx.x * 128;  // x = m-index (XCD grouping)
  const int n0 = blockIdx.y * 128;
  const int lm = lane & 15;
  const int lq = lane >> 4;

  int srow[4], sg[4];
#pragma unroll
  for (int c = 0; c < 4; ++c) {
    const int E = c * 2048 + t * 8;
    srow[c] = E >> 6;
    sg[c] = (((E >> 3) & 7) ^ (srow[c] & 7)) * 8;
  }

  floatx4 acc[4][4];
#pragma unroll
  for (int i = 0; i < 4; ++i)
#pragma unroll
    for (int j = 0; j < 4; ++j) acc[i][j] = (floatx4){0.f, 0.f, 0.f, 0.f};

  for (int k0 = 0; k0 < 1024; k0 += 64) {
    __syncthreads();
#pragma unroll
    for (int c = 0; c < 4; ++c) {
      const int E = c * 2048 + t * 8;
      gload_lds16(X + (size_t)(m0 + srow[c]) * 1024 + k0 + sg[c], As + E);
      gload_lds16(Wt + (size_t)(n0 + srow[c]) * 1024 + k0 + sg[c], Bs + E);
    }
    __syncthreads();

#pragma unroll
    for (int kc = 0; kc < 2; ++kc) {
      bf16x8 a[4], b[4];
#pragma unroll
      for (int i = 0; i < 4; ++i) {
        const int ch = ((kc * 4 + lq) ^ (lm & 7)) * 8;
        a[i] = *(const bf16x8*)(As + (wm + i * 16 + lm) * 64 + ch);
        b[i] = *(const bf16x8*)(Bs + (wn + i * 16 + lm) * 64 + ch);
      }
      if (proj < 2) {
#pragma unroll
        for (int i = 0; i < 4; ++i)
#pragma unroll
          for (int j = 0; j < 4; ++j)
            acc[i][j] = __builtin_amdgcn_mfma_f32_16x16x32_bf16(b[j], a[i],
                                                               acc[i][j], 0, 0, 0);
      } else {
#pragma unroll
        for (int i = 0; i < 4; ++i)
#pragma unroll
          for (int j = 0; j < 4; ++j)
            acc[i][j] = __builtin_amdgcn_mfma_f32_16x16x32_bf16(a[i], b[j],
                                                               acc[i][j], 0, 0, 0);
      }
    }
  }

  if (proj == 2) {
#pragma unroll
    for (int j = 0; j < 4; ++j) {
      const int gn = n0 + wn + j * 16 + lm;
      const float bval = bias[gn];
      const int h = gn >> 6, d = gn & 63;
#pragma unroll
      for (int i = 0; i < 4; ++i) {
        const int gm = m0 + wm + i * 16 + lq * 4;
        const int bb = gm >> 11, s0 = gm & 2047;
        bf16x4 pk;
#pragma unroll
        for (int ii = 0; ii < 4; ++ii) pk[ii] = (bf16_t)(acc[i][j][ii] + bval);
        *(bf16x4*)(Vt + (((size_t)bb * 16 + h) * 64 + d) * 2048 + s0) = pk;
      }
    }
  } else {
    bf16_t* outp = (proj == 0) ? Qh : Kh;
    const float scale = (proj == 0) ? QSCALE : 1.0f;
#pragma unroll
    for (int j = 0; j < 4; ++j) {
      const int nb = n0 + wn + j * 16 + lq * 4;
      float bs4[4];
#pragma unroll
      for (int ii = 0; ii < 4; ++ii) bs4[ii] = bias[nb + ii];
      const int h = nb >> 6, d0 = nb & 63;
#pragma unroll
      for (int i = 0; i < 4; ++i) {
        const int gm = m0 + wm + i * 16 + lm;
        const int bb = gm >> 11, s = gm & 2047;
        bf16x4 pk;
#pragma unroll
        for (int ii = 0; ii < 4; ++ii)
          pk[ii] = (bf16_t)((acc[i][j][ii] + bs4[ii]) * scale);
        *(bf16x4*)(outp + (((size_t)bb * 16 + h) * 2048 + s) * 64 + d0) = pk;
      }
    }
  }
}

// ---------------------------------------------------------------------------
// Kernel 2: flash attention v4 — all components HW-verified: Q-tile 64,
// 4 waves x 16 rows, 256 thr (r8-passed); separate wave-private Ps + 2
// barriers + lgkm drain (r7-passed); c<4 reg-prefetch staging (r7/r8);
// accL ones-MFMA row sum (r8-passed). New: Ps shrunk to [4][16*128] so
// LDS = Ks16+Vs16+Ps16 = 48 KB -> 3 blocks/CU = 12 waves/CU (1.5x r7 TLP),
// and no overlay barrier. grid (32 bh, 32 qt), block 256.
// ---------------------------------------------------------------------------
__global__ __launch_bounds__(256) void attn_k(
    const bf16_t* __restrict__ Qh, const bf16_t* __restrict__ Kh,
    const bf16_t* __restrict__ Vt, float* __restrict__ out) {
  __shared__ __align__(16) bf16_t Ks[128 * 64];     // [key][d], chunk^=key&7
  __shared__ __align__(16) bf16_t Vs[64 * 128];     // [d][key], chunk^=d&15
  __shared__ __align__(16) bf16_t Ps[4][16 * 128];  // per-wave [q][key]

  const int t = threadIdx.x;
  const int lane = t & 63;
  const int w = t >> 6;
  const int lm = lane & 15;
  const int lq = lane >> 4;
  const int b = blockIdx.x >> 4, h = blockIdx.x & 15;  // x = bh (XCD grouping)
  const int q0 = blockIdx.y * 64;
  const size_t bh = (size_t)b * 16 + h;
  const bf16_t* Qb = Qh + bh * (2048 * 64);
  const bf16_t* Kb = Kh + bh * (2048 * 64);
  const bf16_t* Vb = Vt + bh * (64 * 2048);
  bf16_t* Pw = Ps[w];  // wave's 16x128 P slice (wave-private)

  // Q frags (pre-scaled by QSCALE in gemm); B-operand: n=lm, k=lq*8+j
  bf16x8 qf[2];
#pragma unroll
  for (int kc = 0; kc < 2; ++kc)
    qf[kc] = *(const bf16x8*)(Qb + (size_t)(q0 + w * 16 + lm) * 64 + kc * 32 +
                              lq * 8);

  bf16x8 ones;
#pragma unroll
  for (int j = 0; j < 8; ++j) ones[j] = (bf16_t)1.0f;

  floatx4 accO[4], accL;
#pragma unroll
  for (int jd = 0; jd < 4; ++jd) accO[jd] = (floatx4){0.f, 0.f, 0.f, 0.f};
  accL = (floatx4){0.f, 0.f, 0.f, 0.f};

  bf16x8 kv[8];  // [0..3] K-tile chunks, [4..7] V-tile chunks (prefetch regs)

#define LOAD_KV(kt)                                                          \
  {                                                                          \
    _Pragma("unroll") for (int c = 0; c < 4; ++c) {                          \
      const int e = c * 2048 + t * 8;                                        \
      const int key = e >> 6, gk = ((e >> 3) & 7) ^ (key & 7);               \
      kv[c] = *(const bf16x8*)(Kb + (size_t)((kt) + key) * 64 + gk * 8);     \
      const int vr = e >> 7, gv = ((e >> 3) & 15) ^ (vr & 15);               \
      kv[4 + c] = *(const bf16x8*)(Vb + (size_t)vr * 2048 + (kt) + gv * 8);  \
    }                                                                        \
  }

  LOAD_KV(0);

  for (int kt = 0; kt < 2048; kt += 128) {
    __syncthreads();  // all waves done with prev tile's Ks (QK) + Vs (PV)
#pragma unroll
    for (int c = 0; c < 4; ++c) {
      const int e = c * 2048 + t * 8;  // lane-linear
      *(bf16x8*)(Ks + e) = kv[c];
      *(bf16x8*)(Vs + e) = kv[4 + c];
    }
    __syncthreads();  // publish tile

    if (kt + 128 < 2048) LOAD_KV(kt + 128);  // overlaps entire compute below

    // S^T = K @ Q^T : lane holds 4 consecutive keys (rows) x q-col lm
    floatx4 accS[8];
#pragma unroll
    for (int jn = 0; jn < 8; ++jn) {
      const int krow = jn * 16 + lm;
      const bf16x8 k0 = *(const bf16x8*)(Ks + krow * 64 + ((lq) ^ (lm & 7)) * 8);
      const bf16x8 k1 = *(const bf16x8*)(Ks + krow * 64 + ((4 + lq) ^ (lm & 7)) * 8);
      floatx4 z = {0.f, 0.f, 0.f, 0.f};
      z = __builtin_amdgcn_mfma_f32_16x16x32_bf16(k0, qf[0], z, 0, 0, 0);
      z = __builtin_amdgcn_mfma_f32_16x16x32_bf16(k1, qf[1], z, 0, 0, 0);
      accS[jn] = z;
    }

    // p = 2^s ; pack 4 consecutive keys -> one 8B write into wave's P slice
#pragma unroll
    for (int jn = 0; jn < 8; ++jn) {
      bf16x4 pk;
#pragma unroll
      for (int ii = 0; ii < 4; ++ii) pk[ii] = (bf16_t)fast_exp2(accS[jn][ii]);
      const int c2 = ((jn * 2) + (lq >> 1)) ^ lm;  // swizzled key-chunk
      *(bf16x4*)(Pw + lm * 128 + c2 * 8 + (lq & 1) * 4) = pk;
    }
    // P slice is wave-private: wave-local LDS drain suffices
    asm volatile("s_waitcnt lgkmcnt(0)" ::: "memory");

    // O^T = V @ P^T ; l via all-ones A-frag on the MFMA pipe
#pragma unroll
    for (int kc = 0; kc < 4; ++kc) {
      const bf16x8 ap =
          *(const bf16x8*)(Pw + lm * 128 + ((kc * 4 + lq) ^ lm) * 8);
#pragma unroll
      for (int jd = 0; jd < 4; ++jd) {
        const bf16x8 vf = *(const bf16x8*)(Vs + (jd * 16 + lm) * 128 +
                                           ((kc * 4 + lq) ^ lm) * 8);
        accO[jd] = __builtin_amdgcn_mfma_f32_16x16x32_bf16(vf, ap, accO[jd], 0, 0, 0);
      }
      accL = __builtin_amdgcn_mfma_f32_16x16x32_bf16(ones, ap, accL, 0, 0, 0);
    }
  }
#undef LOAD_KV

  // accL rows are identical = l[q=lm]
  const float inv = 1.0f / accL[0];

  // out[b][s][h*64 + d], lane: s = q0+w*16+lm, d = jd*16+lq*4..+3
  const int s = q0 + w * 16 + lm;
  float* op = out + ((size_t)b * 2048 + s) * 1024 + h * 64 + lq * 4;
#pragma unroll
  for (int jd = 0; jd < 4; ++jd) {
    float4 o;
    o.x = accO[jd][0] * inv;
    o.y = accO[jd][1] * inv;
    o.z = accO[jd][2] * inv;
    o.w = accO[jd][3] * inv;
    *(float4*)(op + jd * 16) = o;
  }
}

// ---------------------------------------------------------------------------
extern "C" void kernel_launch(void* const* d_in, const int* in_sizes, int n_in,
                              void* d_out, int out_size, void* d_ws, size_t ws_size,
                              hipStream_t stream) {
  (void)in_sizes; (void)n_in; (void)out_size; (void)ws_size;
  const float* q = (const float*)d_in[0];
  const float* k = (const float*)d_in[1];
  const float* v = (const float*)d_in[2];
  // d_in[3] = mask: additive per-query-row constant under softmax => no-op.
  const float* wq = (const float*)d_in[4];
  const float* bq = (const float*)d_in[5];
  const float* wk = (const float*)d_in[6];
  const float* bk = (const float*)d_in[7];
  const float* wv = (const float*)d_in[8];
  const float* bv = (const float*)d_in[9];
  float* out = (float*)d_out;

  bf16_t* ws = (bf16_t*)d_ws;
  bf16_t* Xb = ws;                   // 3 x 4M bf16 (cast q,k,v)  = 24 MB
  bf16_t* Wt = ws + 12582912u;       // 3 x 1M bf16 (transposed W) = 6 MB
  bf16_t* Qh = Wt + 3145728u;        // 4M [b][h][s][d] (pre-scaled by QSCALE)
  bf16_t* Kh = Qh + 4194304u;        // 4M [b][h][s][d]
  bf16_t* Vt = Kh + 4194304u;        // 4M [b][h][d][s]

  prep_k<<<dim3(3072, 3, 1), dim3(256, 1, 1), 0, stream>>>(
      q, k, v, wq, wk, wv, Xb, Wt);
  qkv_gemm_k<<<dim3(32, 8, 3), dim3(256, 1, 1), 0, stream>>>(
      Xb, Wt, bq, bk, bv, Qh, Kh, Vt);
  attn_k<<<dim3(32, 32, 1), dim3(256, 1, 1), 0, stream>>>(Qh, Kh, Vt, out);
}

// Round 12
// 197.974 us; speedup vs baseline: 1.0326x; 1.0326x over previous
//
#include <hip/hip_runtime.h>
#include <hip/hip_bf16.h>
#include <math.h>

typedef __bf16 bf16_t;
typedef __bf16 bf16x8 __attribute__((ext_vector_type(8)));
typedef __bf16 bf16x4 __attribute__((ext_vector_type(4)));
typedef float floatx4 __attribute__((ext_vector_type(4)));

// Problem: B=2, S=2048, H=1024, NH=16, D=64, M=B*S=4096. All I/O fp32.
// softmax scale 1/32 and log2(e) folded into Q projection epilogue:
#define QSCALE 0.045084222f  // 0.03125 * 1.4426950408889634

__device__ __forceinline__ void gload_lds16(const bf16_t* g, bf16_t* l) {
  __builtin_amdgcn_global_load_lds(
      (const __attribute__((address_space(1))) void*)(g),
      (__attribute__((address_space(3))) void*)(l), 16, 0, 0);
}

__device__ __forceinline__ float fast_exp2(float x) {
  float r;
  asm("v_exp_f32 %0, %1" : "=v"(r) : "v"(x));
  return r;
}

// ---------------------------------------------------------------------------
// Kernel 0: prep (merged). blocks x<2048: cast q/k/v fp32->bf16 contiguous.
// blocks x>=2048: transpose+cast wq/wk/wv [K][N] -> bf16 [N][K].
// grid (3072, 3), block 256.  [HW-verified r8/r10]
// ---------------------------------------------------------------------------
__global__ __launch_bounds__(256) void prep_k(
    const float* __restrict__ q, const float* __restrict__ k,
    const float* __restrict__ v, const float* __restrict__ wq,
    const float* __restrict__ wk, const float* __restrict__ wv,
    bf16_t* __restrict__ xb, bf16_t* __restrict__ wt) {
  const int z = blockIdx.y;
  const int t = threadIdx.x;
  if (blockIdx.x < 2048) {
    const float* src = (z == 0) ? q : (z == 1) ? k : v;
    bf16_t* dst = xb + (size_t)z * 4194304u;
    const int i = (blockIdx.x * 256 + t) * 8;
    float4 f0 = *(const float4*)(src + i);
    float4 f1 = *(const float4*)(src + i + 4);
    bf16x8 hv;
    hv[0] = (bf16_t)f0.x; hv[1] = (bf16_t)f0.y;
    hv[2] = (bf16_t)f0.z; hv[3] = (bf16_t)f0.w;
    hv[4] = (bf16_t)f1.x; hv[5] = (bf16_t)f1.y;
    hv[6] = (bf16_t)f1.z; hv[7] = (bf16_t)f1.w;
    *(bf16x8*)(dst + i) = hv;
  } else {
    __shared__ float tile[32][33];
    const int bi = blockIdx.x - 2048;
    const int bx = bi & 31, by = bi >> 5;
    const float* src = (z == 0) ? wq : (z == 1) ? wk : wv;
    bf16_t* dst = wt + (size_t)z * 1048576u;
    const int tx = t & 31, ty = t >> 5;
    const int x = bx * 32 + tx, y = by * 32 + ty;
#pragma unroll
    for (int i = 0; i < 32; i += 8)
      tile[ty + i][tx] = src[(size_t)(y + i) * 1024 + x];
    __syncthreads();
    const int x2 = by * 32 + tx, y2 = bx * 32 + ty;
#pragma unroll
    for (int i = 0; i < 32; i += 8)
      dst[(size_t)(y2 + i) * 1024 + x2] = (bf16_t)tile[tx][ty + i];
  }
}

// ---------------------------------------------------------------------------
// Kernel 1: C = Xb @ W + b, m97-style. [HW-verified r7-r10, unchanged]
// ---------------------------------------------------------------------------
__global__ __launch_bounds__(256) void qkv_gemm_k(
    const bf16_t* __restrict__ xb3, const bf16_t* __restrict__ wt3,
    const float* __restrict__ bq, const float* __restrict__ bk,
    const float* __restrict__ bv, bf16_t* __restrict__ Qh,
    bf16_t* __restrict__ Kh, bf16_t* __restrict__ Vt) {
  const int proj = blockIdx.z;
  const bf16_t* X = xb3 + (size_t)proj * 4194304u;
  const bf16_t* Wt = wt3 + (size_t)proj * 1048576u;
  const float* bias = (proj == 0) ? bq : (proj == 1) ? bk : bv;

  __shared__ __align__(16) bf16_t As[128 * 64];  // 16 KB
  __shared__ __align__(16) bf16_t Bs[128 * 64];  // 16 KB

  const int t = threadIdx.x;
  const int lane = t & 63;
  const int w = t >> 6;
  const int wm = (w >> 1) * 64;
  const int wn = (w & 1) * 64;
  const int m0 = blockIdx.x * 128;  // x = m-index (XCD grouping)
  const int n0 = blockIdx.y * 128;
  const int lm = lane & 15;
  const int lq = lane >> 4;

  int srow[4], sg[4];
#pragma unroll
  for (int c = 0; c < 4; ++c) {
    const int E = c * 2048 + t * 8;
    srow[c] = E >> 6;
    sg[c] = (((E >> 3) & 7) ^ (srow[c] & 7)) * 8;
  }

  floatx4 acc[4][4];
#pragma unroll
  for (int i = 0; i < 4; ++i)
#pragma unroll
    for (int j = 0; j < 4; ++j) acc[i][j] = (floatx4){0.f, 0.f, 0.f, 0.f};

  for (int k0 = 0; k0 < 1024; k0 += 64) {
    __syncthreads();
#pragma unroll
    for (int c = 0; c < 4; ++c) {
      const int E = c * 2048 + t * 8;
      gload_lds16(X + (size_t)(m0 + srow[c]) * 1024 + k0 + sg[c], As + E);
      gload_lds16(Wt + (size_t)(n0 + srow[c]) * 1024 + k0 + sg[c], Bs + E);
    }
    __syncthreads();

#pragma unroll
    for (int kc = 0; kc < 2; ++kc) {
      bf16x8 a[4], b[4];
#pragma unroll
      for (int i = 0; i < 4; ++i) {
        const int ch = ((kc * 4 + lq) ^ (lm & 7)) * 8;
        a[i] = *(const bf16x8*)(As + (wm + i * 16 + lm) * 64 + ch);
        b[i] = *(const bf16x8*)(Bs + (wn + i * 16 + lm) * 64 + ch);
      }
      if (proj < 2) {
#pragma unroll
        for (int i = 0; i < 4; ++i)
#pragma unroll
          for (int j = 0; j < 4; ++j)
            acc[i][j] = __builtin_amdgcn_mfma_f32_16x16x32_bf16(b[j], a[i],
                                                               acc[i][j], 0, 0, 0);
      } else {
#pragma unroll
        for (int i = 0; i < 4; ++i)
#pragma unroll
          for (int j = 0; j < 4; ++j)
            acc[i][j] = __builtin_amdgcn_mfma_f32_16x16x32_bf16(a[i], b[j],
                                                               acc[i][j], 0, 0, 0);
      }
    }
  }

  if (proj == 2) {
#pragma unroll
    for (int j = 0; j < 4; ++j) {
      const int gn = n0 + wn + j * 16 + lm;
      const float bval = bias[gn];
      const int h = gn >> 6, d = gn & 63;
#pragma unroll
      for (int i = 0; i < 4; ++i) {
        const int gm = m0 + wm + i * 16 + lq * 4;
        const int bb = gm >> 11, s0 = gm & 2047;
        bf16x4 pk;
#pragma unroll
        for (int ii = 0; ii < 4; ++ii) pk[ii] = (bf16_t)(acc[i][j][ii] + bval);
        *(bf16x4*)(Vt + (((size_t)bb * 16 + h) * 64 + d) * 2048 + s0) = pk;
      }
    }
  } else {
    bf16_t* outp = (proj == 0) ? Qh : Kh;
    const float scale = (proj == 0) ? QSCALE : 1.0f;
#pragma unroll
    for (int j = 0; j < 4; ++j) {
      const int nb = n0 + wn + j * 16 + lq * 4;
      float bs4[4];
#pragma unroll
      for (int ii = 0; ii < 4; ++ii) bs4[ii] = bias[nb + ii];
      const int h = nb >> 6, d0 = nb & 63;
#pragma unroll
      for (int i = 0; i < 4; ++i) {
        const int gm = m0 + wm + i * 16 + lm;
        const int bb = gm >> 11, s = gm & 2047;
        bf16x4 pk;
#pragma unroll
        for (int ii = 0; ii < 4; ++ii)
          pk[ii] = (bf16_t)((acc[i][j][ii] + bs4[ii]) * scale);
        *(bf16x4*)(outp + (((size_t)bb * 16 + h) * 2048 + s) * 64 + d0) = pk;
      }
    }
  }
}

// ---------------------------------------------------------------------------
// Kernel 2: flash attention — r7's fastest verified version (Q-tile 128,
// 4 waves x 32 rows, V staged in LDS, wave-private Ps, register K/V
// prefetch; 56.9 us measured) with ONE verified delta: the VALU lsum
// (64 adds + 4 shuffles per tile) is replaced by accL all-ones-MFMA row
// sums (verified correct in r8/r10 runs). grid (32 bh, 16 qt), block 256.
// ---------------------------------------------------------------------------
__global__ __launch_bounds__(256) void attn_k(
    const bf16_t* __restrict__ Qh, const bf16_t* __restrict__ Kh,
    const bf16_t* __restrict__ Vt, float* __restrict__ out) {
  __shared__ __align__(16) bf16_t Ks[128 * 64];     // [key][d],  chunk^= key&7
  __shared__ __align__(16) bf16_t Vs[64 * 128];     // [d][key],  chunk^= d&15
  __shared__ __align__(16) bf16_t Ps[4][32 * 128];  // per-wave P [q][key]

  const int t = threadIdx.x;
  const int lane = t & 63;
  const int w = t >> 6;
  const int lm = lane & 15;
  const int lq = lane >> 4;
  const int b = blockIdx.x >> 4, h = blockIdx.x & 15;  // x = bh (XCD grouping)
  const int q0 = blockIdx.y * 128;
  const size_t bh = (size_t)b * 16 + h;
  const bf16_t* Qb = Qh + bh * (2048 * 64);
  const bf16_t* Kb = Kh + bh * (2048 * 64);
  const bf16_t* Vb = Vt + bh * (64 * 2048);

  // Q frags (pre-scaled by QSCALE in gemm); B-operand: n=lm, k=lq*8+j
  bf16x8 qf[2][2];
#pragma unroll
  for (int im = 0; im < 2; ++im)
#pragma unroll
    for (int kc = 0; kc < 2; ++kc)
      qf[im][kc] = *(const bf16x8*)(Qb +
          (size_t)(q0 + w * 32 + im * 16 + lm) * 64 + kc * 32 + lq * 8);

  bf16x8 ones;
#pragma unroll
  for (int j = 0; j < 8; ++j) ones[j] = (bf16_t)1.0f;

  floatx4 accO[2][4], accL[2];
#pragma unroll
  for (int im = 0; im < 2; ++im) {
#pragma unroll
    for (int jd = 0; jd < 4; ++jd) accO[im][jd] = (floatx4){0.f, 0.f, 0.f, 0.f};
    accL[im] = (floatx4){0.f, 0.f, 0.f, 0.f};
  }

  bf16x8 kv[8];  // [0..3] K-tile chunks, [4..7] V-tile chunks (prefetch regs)

#define LOAD_KV(kt)                                                          \
  {                                                                          \
    _Pragma("unroll") for (int c = 0; c < 4; ++c) {                          \
      const int e = c * 2048 + t * 8;                                        \
      const int key = e >> 6, gk = ((e >> 3) & 7) ^ (key & 7);               \
      kv[c] = *(const bf16x8*)(Kb + (size_t)((kt) + key) * 64 + gk * 8);     \
      const int vr = e >> 7, gv = ((e >> 3) & 15) ^ (vr & 15);               \
      kv[4 + c] = *(const bf16x8*)(Vb + (size_t)vr * 2048 + (kt) + gv * 8);  \
    }                                                                        \
  }

  LOAD_KV(0);

  for (int kt = 0; kt < 2048; kt += 128) {
    __syncthreads();  // all waves done reading Ks/Vs of prev tile
#pragma unroll
    for (int c = 0; c < 4; ++c) {
      const int e = c * 2048 + t * 8;  // lane-linear
      *(bf16x8*)(Ks + e) = kv[c];
      *(bf16x8*)(Vs + e) = kv[4 + c];
    }
    __syncthreads();  // publish tile

    if (kt + 128 < 2048) LOAD_KV(kt + 128);  // overlaps entire compute below

    // S^T = K @ Q^T : lane holds 4 consecutive keys (rows) x q-col lm
    floatx4 accS[2][8];
#pragma unroll
    for (int jn = 0; jn < 8; ++jn) {
      const int krow = jn * 16 + lm;
      const bf16x8 k0 = *(const bf16x8*)(Ks + krow * 64 + ((lq) ^ (lm & 7)) * 8);
      const bf16x8 k1 = *(const bf16x8*)(Ks + krow * 64 + ((4 + lq) ^ (lm & 7)) * 8);
#pragma unroll
      for (int im = 0; im < 2; ++im) {
        floatx4 z = {0.f, 0.f, 0.f, 0.f};
        z = __builtin_amdgcn_mfma_f32_16x16x32_bf16(k0, qf[im][0], z, 0, 0, 0);
        z = __builtin_amdgcn_mfma_f32_16x16x32_bf16(k1, qf[im][1], z, 0, 0, 0);
        accS[im][jn] = z;
      }
    }

    // p = 2^s ; pack 4 consecutive keys -> one 8B write into wave's P slice
#pragma unroll
    for (int im = 0; im < 2; ++im) {
      const int pr = im * 16 + lm;  // q-row owned by this lane
#pragma unroll
      for (int jn = 0; jn < 8; ++jn) {
        bf16x4 pk;
#pragma unroll
        for (int ii = 0; ii < 4; ++ii) pk[ii] = (bf16_t)fast_exp2(accS[im][jn][ii]);
        const int c2 = ((jn * 2) + (lq >> 1)) ^ lm;  // swizzled key-chunk
        *(bf16x4*)(Ps[w] + pr * 128 + c2 * 8 + (lq & 1) * 4) = pk;
      }
    }
    // P slice is wave-private: wave-local LDS drain suffices
    asm volatile("s_waitcnt lgkmcnt(0)" ::: "memory");

    // O^T = V @ P^T ; l via all-ones A-frag on the MFMA pipe
#pragma unroll
    for (int kc = 0; kc < 4; ++kc) {
      bf16x8 ap[2];
#pragma unroll
      for (int im = 0; im < 2; ++im)
        ap[im] = *(const bf16x8*)(Ps[w] + (im * 16 + lm) * 128 +
                                  ((kc * 4 + lq) ^ lm) * 8);
#pragma unroll
      for (int jd = 0; jd < 4; ++jd) {
        const bf16x8 vf = *(const bf16x8*)(Vs + (jd * 16 + lm) * 128 +
                                           ((kc * 4 + lq) ^ lm) * 8);
#pragma unroll
        for (int im = 0; im < 2; ++im)
          accO[im][jd] =
              __builtin_amdgcn_mfma_f32_16x16x32_bf16(vf, ap[im], accO[im][jd], 0, 0, 0);
      }
#pragma unroll
      for (int im = 0; im < 2; ++im)
        accL[im] = __builtin_amdgcn_mfma_f32_16x16x32_bf16(ones, ap[im],
                                                           accL[im], 0, 0, 0);
    }
  }
#undef LOAD_KV

  // accL[im] rows identical = l for q-row im*16+lm (matches accO's rows)
  float inv[2];
#pragma unroll
  for (int im = 0; im < 2; ++im) inv[im] = 1.0f / accL[im][0];

  // out[b][s][h*64 + d], lane: s = q0+w*32+im*16+lm, d = jd*16+lq*4..+3
#pragma unroll
  for (int im = 0; im < 2; ++im) {
    const int s = q0 + w * 32 + im * 16 + lm;
    float* op = out + ((size_t)b * 2048 + s) * 1024 + h * 64 + lq * 4;
#pragma unroll
    for (int jd = 0; jd < 4; ++jd) {
      float4 o;
      o.x = accO[im][jd][0] * inv[im];
      o.y = accO[im][jd][1] * inv[im];
      o.z = accO[im][jd][2] * inv[im];
      o.w = accO[im][jd][3] * inv[im];
      *(float4*)(op + jd * 16) = o;
    }
  }
}

// ---------------------------------------------------------------------------
extern "C" void kernel_launch(void* const* d_in, const int* in_sizes, int n_in,
                              void* d_out, int out_size, void* d_ws, size_t ws_size,
                              hipStream_t stream) {
  (void)in_sizes; (void)n_in; (void)out_size; (void)ws_size;
  const float* q = (const float*)d_in[0];
  const float* k = (const float*)d_in[1];
  const float* v = (const float*)d_in[2];
  // d_in[3] = mask: additive per-query-row constant under softmax => no-op.
  const float* wq = (const float*)d_in[4];
  const float* bq = (const float*)d_in[5];
  const float* wk = (const float*)d_in[6];
  const float* bk = (const float*)d_in[7];
  const float* wv = (const float*)d_in[8];
  const float* bv = (const float*)d_in[9];
  float* out = (float*)d_out;

  bf16_t* ws = (bf16_t*)d_ws;
  bf16_t* Xb = ws;                   // 3 x 4M bf16 (cast q,k,v)  = 24 MB
  bf16_t* Wt = ws + 12582912u;       // 3 x 1M bf16 (transposed W) = 6 MB
  bf16_t* Qh = Wt + 3145728u;        // 4M [b][h][s][d] (pre-scaled by QSCALE)
  bf16_t* Kh = Qh + 4194304u;        // 4M [b][h][s][d]
  bf16_t* Vt = Kh + 4194304u;        // 4M [b][h][d][s]

  prep_k<<<dim3(3072, 3, 1), dim3(256, 1, 1), 0, stream>>>(
      q, k, v, wq, wk, wv, Xb, Wt);
  qkv_gemm_k<<<dim3(32, 8, 3), dim3(256, 1, 1), 0, stream>>>(
      Xb, Wt, bq, bk, bv, Qh, Kh, Vt);
  attn_k<<<dim3(32, 16, 1), dim3(256, 1, 1), 0, stream>>>(Qh, Kh, Vt, out);
}